// Round 6
// baseline (431.401 us; speedup 1.0000x reference)
//
#include <hip/hip_runtime.h>
#include <hip/hip_bf16.h>

#define N_ATOMS 10000
#define N_PAIR  100000
#define F_DIM   128
#define N_HEAD  4
#define FH      32
#define N_DEG   3
#define M_TOT   15
#define K_RBF   32
#define R_OUT   (N_ATOMS * M_TOT)   // 150000 rows in the output GEMM

typedef __attribute__((ext_vector_type(8))) short short8;   // 8 bf16 = 4 VGPRs
typedef __attribute__((ext_vector_type(4))) float f32x4;

union frag_cast { int i[4]; short8 s; };

__device__ __forceinline__ float sspf(float v) {
    float sp = fmaxf(v, 0.f) + log1pf(expf(-fabsf(v)));
    return sp - 0.69314718055994531f;
}

__device__ __forceinline__ unsigned short bf16_rne(float x) {
    unsigned int u = __float_as_uint(x);
    unsigned int r = u + 0x7fffu + ((u >> 16) & 1u);
    return (unsigned short)(r >> 16);
}
__device__ __forceinline__ float bf16_tof(unsigned short h) {
    return __uint_as_float(((unsigned int)h) << 16);
}

// ---------------- Generic 128-col GEMM (fp32, used for x@W_in only) ---------
__global__ __launch_bounds__(256) void k_gemm128(
    const float* __restrict__ A, const float* __restrict__ B,
    const float* __restrict__ bias, float* __restrict__ C, int rows)
{
    __shared__ float As[32][132];
    __shared__ float Bs[32][132];
    int r0 = blockIdx.x * 128;
    int t = threadIdx.x;
    int ty = t >> 4, tx = t & 15;

    float acc[8][8];
    #pragma unroll
    for (int i = 0; i < 8; ++i)
        #pragma unroll
        for (int j = 0; j < 8; ++j) acc[i][j] = 0.f;

    for (int k0 = 0; k0 < 128; k0 += 32) {
        #pragma unroll
        for (int r = 0; r < 16; ++r) {
            int idx = t + 256 * r;
            int row = idx >> 5, kk = idx & 31;
            int grow = r0 + row;
            As[kk][row] = (grow < rows) ? A[grow * 128 + k0 + kk] : 0.f;
        }
        #pragma unroll
        for (int r = 0; r < 16; ++r) {
            int idx = t + 256 * r;
            int kk = idx >> 7, c = idx & 127;
            Bs[kk][c] = B[(k0 + kk) * 128 + c];
        }
        __syncthreads();

        #pragma unroll
        for (int kk = 0; kk < 32; ++kk) {
            float a[8], b[8];
            *(float4*)&a[0] = *(const float4*)&As[kk][ty * 4];
            *(float4*)&a[4] = *(const float4*)&As[kk][64 + ty * 4];
            *(float4*)&b[0] = *(const float4*)&Bs[kk][tx * 4];
            *(float4*)&b[4] = *(const float4*)&Bs[kk][64 + tx * 4];
            #pragma unroll
            for (int i = 0; i < 8; ++i)
                #pragma unroll
                for (int j = 0; j < 8; ++j)
                    acc[i][j] = fmaf(a[i], b[j], acc[i][j]);
        }
        __syncthreads();
    }

    float bj[8];
    #pragma unroll
    for (int j = 0; j < 4; ++j) { bj[j] = bias[tx * 4 + j]; bj[4 + j] = bias[64 + tx * 4 + j]; }

    #pragma unroll
    for (int i = 0; i < 8; ++i) {
        int row = r0 + ((i < 4) ? (ty * 4 + i) : (64 + ty * 4 + (i - 4)));
        if (row < rows) {
            float4 v0, v1;
            v0.x = acc[i][0] + bj[0]; v0.y = acc[i][1] + bj[1];
            v0.z = acc[i][2] + bj[2]; v0.w = acc[i][3] + bj[3];
            v1.x = acc[i][4] + bj[4]; v1.y = acc[i][5] + bj[5];
            v1.z = acc[i][6] + bj[6]; v1.w = acc[i][7] + bj[7];
            *(float4*)&C[row * 128 + tx * 4] = v0;
            *(float4*)&C[row * 128 + 64 + tx * 4] = v1;
        }
    }
}

// ---------------- Q/K projection: 32 atoms/block (313 blocks) ---------------
__global__ __launch_bounds__(384) void k_qk(
    const float* __restrict__ xh, const float* __restrict__ W_Q,
    const float* __restrict__ W_K, float* __restrict__ Q, float* __restrict__ K)
{
    __shared__ float xfs[32][128];
    int t = threadIdx.x;                 // == e
    int h = (t >> 5) & 3;
    float wq[32], wk[32];
    const float4* wqp = (const float4*)(W_Q + t * 32);
    const float4* wkp = (const float4*)(W_K + t * 32);
    #pragma unroll
    for (int j4 = 0; j4 < 8; ++j4) {
        float4 a = wqp[j4], b = wkp[j4];
        wq[4 * j4 + 0] = a.x; wq[4 * j4 + 1] = a.y; wq[4 * j4 + 2] = a.z; wq[4 * j4 + 3] = a.w;
        wk[4 * j4 + 0] = b.x; wk[4 * j4 + 1] = b.y; wk[4 * j4 + 2] = b.z; wk[4 * j4 + 3] = b.w;
    }
    int ab = blockIdx.x * 32;
    for (int idx = t; idx < 4096; idx += 384) {
        int aa = idx >> 7, f = idx & 127;
        int ag = ab + aa;
        xfs[aa][f] = (ag < N_ATOMS) ? xh[ag * 128 + f] : 0.f;
    }
    __syncthreads();
    for (int aa = 0; aa < 32; ++aa) {
        int ag = ab + aa;
        if (ag >= N_ATOMS) break;
        const float4* xv = (const float4*)&xfs[aa][h * 32];
        float q0 = 0.f, q1 = 0.f, k0 = 0.f, k1 = 0.f;
        #pragma unroll
        for (int j4 = 0; j4 < 8; j4 += 2) {
            float4 x0 = xv[j4], x1 = xv[j4 + 1];
            q0 = fmaf(wq[4 * j4 + 0], x0.x, q0); q0 = fmaf(wq[4 * j4 + 1], x0.y, q0);
            q0 = fmaf(wq[4 * j4 + 2], x0.z, q0); q0 = fmaf(wq[4 * j4 + 3], x0.w, q0);
            q1 = fmaf(wq[4 * j4 + 4], x1.x, q1); q1 = fmaf(wq[4 * j4 + 5], x1.y, q1);
            q1 = fmaf(wq[4 * j4 + 6], x1.z, q1); q1 = fmaf(wq[4 * j4 + 7], x1.w, q1);
            k0 = fmaf(wk[4 * j4 + 0], x0.x, k0); k0 = fmaf(wk[4 * j4 + 1], x0.y, k0);
            k0 = fmaf(wk[4 * j4 + 2], x0.z, k0); k0 = fmaf(wk[4 * j4 + 3], x0.w, k0);
            k1 = fmaf(wk[4 * j4 + 4], x1.x, k1); k1 = fmaf(wk[4 * j4 + 5], x1.y, k1);
            k1 = fmaf(wk[4 * j4 + 6], x1.z, k1); k1 = fmaf(wk[4 * j4 + 7], x1.w, k1);
        }
        Q[ag * 384 + t] = q0 + q1;
        K[ag * 384 + t] = k0 + k1;
    }
}

// ---------------- h1 = ssp(rbf @ W_f1 + b_f1) to global (staged in d_out) ---
__global__ __launch_bounds__(256) void k_h1(
    const float* __restrict__ rbf, const float* __restrict__ W_f1,
    const float* __restrict__ b_f1, float* __restrict__ h1g)
{
    __shared__ float wf1s[32][33];
    __shared__ float b1s[32];
    __shared__ float rbf_s[64][33];
    int t = threadIdx.x;
    int p0 = blockIdx.x * 64;
    for (int idx = t; idx < 1024; idx += 256) wf1s[idx >> 5][idx & 31] = W_f1[idx];
    if (t < 32) b1s[t] = b_f1[t];
    for (int idx = t; idx < 2048; idx += 256) {
        int pp = idx >> 5, l = idx & 31;
        int pg = p0 + pp;
        rbf_s[pp][l] = (pg < N_PAIR) ? rbf[pg * 32 + l] : 0.f;
    }
    __syncthreads();
    for (int idx = t; idx < 2048; idx += 256) {
        int pp = idx >> 5, l = idx & 31;
        float acc = b1s[l];
        #pragma unroll
        for (int k = 0; k < 32; ++k)
            acc = fmaf(rbf_s[pp][k], wf1s[k][l], acc);
        int pg = p0 + pp;
        if (pg < N_PAIR) h1g[(size_t)pg * 32 + l] = sspf(acc);
    }
}

// ---------------- Pair kernel: SGPR h1, 2 cols/thread, width-16 reduce ------
// h1[p] is wave-uniform -> scalar loads (no DS pipe); W_f2 cols in VGPRs.
__global__ __launch_bounds__(384, 3) void k_pair(
    const float* __restrict__ phi, const float* __restrict__ mask,
    const int* __restrict__ idx_i, const int* __restrict__ idx_j,
    const float* __restrict__ W_f2, const float* __restrict__ b_f2,
    const float* __restrict__ h1g, const float* __restrict__ Q,
    const float* __restrict__ K, float* __restrict__ alpha)
{
    __shared__ float phi_s[64];
    __shared__ float m_s[64];
    __shared__ int   i_s[64];
    __shared__ int   j_s[64];
    __shared__ float alpha_s[768];

    int t = threadIdx.x;
    int p0 = blockIdx.x * 64;
    int pr = __builtin_amdgcn_readfirstlane(t / 192);   // wave-uniform parity
    int c  = t % 192;
    int dh = c >> 4;             // 0..11
    int f0 = c & 15;
    int e0 = dh * 32 + f0;
    int e1 = e0 + 16;

    float wf2a[32], wf2b[32];
    #pragma unroll
    for (int k = 0; k < 32; ++k) {
        wf2a[k] = W_f2[k * 384 + e0];
        wf2b[k] = W_f2[k * 384 + e1];
    }
    float b2a = b_f2[e0], b2b = b_f2[e1];

    if (t < 64) {
        int pg = p0 + t;
        bool v = pg < N_PAIR;
        phi_s[t] = v ? phi[pg] : 0.f;
        m_s[t]   = v ? mask[pg] : 0.f;
        i_s[t]   = v ? idx_i[pg] : 0;
        j_s[t]   = v ? idx_j[pg] : 0;
    }
    __syncthreads();

    // h1 current/next in (hopefully) SGPRs via wave-uniform address
    float hC[32], hN[32];
    {
        const float* hp = h1g + (size_t)(p0 + pr) * 32;
        #pragma unroll
        for (int k = 0; k < 32; ++k) hC[k] = hp[k];
    }
    int ic = i_s[pr], jc = j_s[pr];
    float qa = Q[ic * 384 + e0], qb = Q[ic * 384 + e1];
    float ka = K[jc * 384 + e0], kb = K[jc * 384 + e1];

    for (int pb = 0; pb < 64; pb += 2) {
        int p = pb + pr;
        float nqa, nqb, nka, nkb;
        if (pb < 62) {
            int pn = p + 2;
            const float* hp = h1g + (size_t)(p0 + pn) * 32;
            #pragma unroll
            for (int k = 0; k < 32; ++k) hN[k] = hp[k];
            int in_ = i_s[pn], jn = j_s[pn];
            nqa = Q[in_ * 384 + e0]; nqb = Q[in_ * 384 + e1];
            nka = K[jn * 384 + e0]; nkb = K[jn * 384 + e1];
        }
        float w0 = b2a, w1 = b2b;
        #pragma unroll
        for (int k = 0; k < 32; ++k) {
            w0 = fmaf(hC[k], wf2a[k], w0);
            w1 = fmaf(hC[k], wf2b[k], w1);
        }
        float part = (qa * ka * w0 + qb * kb * w1) * phi_s[p];
        #pragma unroll
        for (int off = 8; off >= 1; off >>= 1)
            part += __shfl_xor(part, off, 16);
        if (f0 == 0) {
            float m = m_s[p];
            alpha_s[p * 12 + dh] = part * m * m * 0.17677669529663687f;
        }
        if (pb < 62) {
            #pragma unroll
            for (int k = 0; k < 32; ++k) hC[k] = hN[k];
            qa = nqa; qb = nqb; ka = nka; kb = nkb;
        }
    }
    __syncthreads();
    #pragma unroll
    for (int r = 0; r < 2; ++r) {
        int idx = t + r * 384;
        long g = (long)p0 * 12 + idx;
        if (g < (long)N_PAIR * 12) alpha[g] = alpha_s[idx];
    }
}

__device__ __forceinline__ int lower_bound_i(const int* __restrict__ arr, int n, int val) {
    int lo = 0, hi = n;
    while (lo < hi) {
        int mid = (lo + hi) >> 1;
        if (arr[mid] < val) lo = mid + 1; else hi = mid;
    }
    return lo;
}

__global__ __launch_bounds__(256) void k_seg(const int* __restrict__ idx_i,
                                             int* __restrict__ seg)
{
    int a = blockIdx.x * 256 + threadIdx.x;
    if (a <= N_ATOMS) seg[a] = lower_bound_i(idx_i, N_PAIR, a);
}

// ---------------- W_out -> transposed hi/lo bf16 ----------------------------
__global__ __launch_bounds__(256) void k_cvt_b(
    const float* __restrict__ W, unsigned short* __restrict__ Bth,
    unsigned short* __restrict__ Btl)
{
    int idx = blockIdx.x * 256 + threadIdx.x;   // 16384 total
    int cc = idx >> 7, kk = idx & 127;
    float v = W[kk * 128 + cc];                 // transpose read
    unsigned short h = bf16_rne(v);
    unsigned short l = bf16_rne(v - bf16_tof(h));
    Bth[cc * 128 + kk] = h;
    Btl[cc * 128 + kk] = l;
}

// ---------------- Segment aggregation (R4 form): 2 groups, 256 threads ------
__global__ __launch_bounds__(256) void k_agg(
    const float* __restrict__ xh, const float* __restrict__ alpha,
    const float* __restrict__ sph, const int* __restrict__ seg,
    const int* __restrict__ idx_j, const float* __restrict__ mask,
    unsigned int* __restrict__ aggp)
{
    __shared__ float red[15][132];
    int a = blockIdx.x;
    int t = threadIdx.x & 127;
    int grp = threadIdx.x >> 7;
    int h = t >> 5;
    int lo = seg[a], hi = seg[a + 1];

    float acc[15];
    #pragma unroll
    for (int m = 0; m < 15; ++m) acc[m] = 0.f;

    int p = lo + grp;
    float x_cur = 0.f;
    if (p < hi) x_cur = xh[idx_j[p] * 128 + t];
    for (; p < hi; p += 2) {
        int pn = p + 2;
        float x_nxt = 0.f;
        if (pn < hi) x_nxt = xh[idx_j[pn] * 128 + t];
        float xj = x_cur * mask[p];
        float a0v = alpha[p * 12 + h];
        float a1v = alpha[p * 12 + 4 + h];
        float a2v = alpha[p * 12 + 8 + h];
        const float* sp = sph + p * 15;
        #pragma unroll
        for (int m = 0; m < 15; ++m) {
            float al = (m < 3) ? a0v : ((m < 8) ? a1v : a2v);
            acc[m] = fmaf(sp[m] * al, xj, acc[m]);
        }
        x_cur = x_nxt;
    }

    if (grp == 1) {
        #pragma unroll
        for (int m = 0; m < 15; ++m) red[m][t] = acc[m];
    }
    __syncthreads();
    if (grp == 0) {
        #pragma unroll
        for (int m = 0; m < 15; ++m) {
            float v = acc[m] + red[m][t];
            unsigned short hh = bf16_rne(v);
            unsigned short ll = bf16_rne(v - bf16_tof(hh));
            aggp[(a * 15 + m) * 128 + t] = ((unsigned int)hh << 16) | (unsigned int)ll;
        }
    }
}

// ---------------- out = agg @ W_out + b_out via bf16x3 MFMA -----------------
__global__ __launch_bounds__(256) void k_out_mfma(
    const unsigned int* __restrict__ Apack,
    const unsigned short* __restrict__ Bth, const unsigned short* __restrict__ Btl,
    const float* __restrict__ bias, float* __restrict__ C)
{
    int t = threadIdx.x;
    int wave = t >> 6, lane = t & 63;
    int quad = lane >> 4, l15 = lane & 15;
    long rowbase = (long)blockIdx.x * 128 + wave * 32;

    short8 ah[2][4], al[2][4];
    #pragma unroll
    for (int rt = 0; rt < 2; ++rt) {
        long row = rowbase + rt * 16 + l15;
        if (row > R_OUT - 1) row = R_OUT - 1;
        #pragma unroll
        for (int ks = 0; ks < 4; ++ks) {
            const uint4* ap = (const uint4*)(Apack + row * 128 + ks * 32 + quad * 8);
            uint4 u01 = ap[0], u23 = ap[1];
            unsigned int u[8] = {u01.x, u01.y, u01.z, u01.w, u23.x, u23.y, u23.z, u23.w};
            frag_cast fh, fl;
            #pragma unroll
            for (int q = 0; q < 4; ++q) {
                unsigned int a0 = u[2 * q], a1 = u[2 * q + 1];
                fh.i[q] = (int)((a0 >> 16) | (a1 & 0xffff0000u));
                fl.i[q] = (int)((a0 & 0xffffu) | (a1 << 16));
            }
            ah[rt][ks] = fh.s;
            al[rt][ks] = fl.s;
        }
    }

    #pragma unroll 2
    for (int nt = 0; nt < 8; ++nt) {
        int colbase = nt * 16;
        short8 bh[4], bl[4];
        #pragma unroll
        for (int ks = 0; ks < 4; ++ks) {
            int off = (colbase + l15) * 128 + ks * 32 + quad * 8;
            bh[ks] = *(const short8*)(Bth + off);
            bl[ks] = *(const short8*)(Btl + off);
        }
        f32x4 acc0 = {0.f, 0.f, 0.f, 0.f};
        f32x4 acc1 = {0.f, 0.f, 0.f, 0.f};
        #pragma unroll
        for (int ks = 0; ks < 4; ++ks) {
            acc0 = __builtin_amdgcn_mfma_f32_16x16x32_bf16(ah[0][ks], bh[ks], acc0, 0, 0, 0);
            acc1 = __builtin_amdgcn_mfma_f32_16x16x32_bf16(ah[1][ks], bh[ks], acc1, 0, 0, 0);
            acc0 = __builtin_amdgcn_mfma_f32_16x16x32_bf16(al[0][ks], bh[ks], acc0, 0, 0, 0);
            acc1 = __builtin_amdgcn_mfma_f32_16x16x32_bf16(al[1][ks], bh[ks], acc1, 0, 0, 0);
            acc0 = __builtin_amdgcn_mfma_f32_16x16x32_bf16(ah[0][ks], bl[ks], acc0, 0, 0, 0);
            acc1 = __builtin_amdgcn_mfma_f32_16x16x32_bf16(ah[1][ks], bl[ks], acc1, 0, 0, 0);
        }
        float bv = bias[colbase + l15];
        #pragma unroll
        for (int r = 0; r < 4; ++r) {
            long row0 = rowbase + quad * 4 + r;
            long row1 = rowbase + 16 + quad * 4 + r;
            if (row0 < R_OUT) C[row0 * 128 + colbase + l15] = acc0[r] + bv;
            if (row1 < R_OUT) C[row1 * 128 + colbase + l15] = acc1[r] + bv;
        }
    }
}

extern "C" void kernel_launch(void* const* d_in, const int* in_sizes, int n_in,
                              void* d_out, int out_size, void* d_ws, size_t ws_size,
                              hipStream_t stream) {
    const float* x        = (const float*)d_in[0];
    const float* rbf_ij   = (const float*)d_in[1];
    const float* sph_ij   = (const float*)d_in[2];
    const float* phi_r    = (const float*)d_in[3];
    const int*   idx_i    = (const int*)d_in[4];
    const int*   idx_j    = (const int*)d_in[5];
    const float* pmask    = (const float*)d_in[6];
    const float* W_Q      = (const float*)d_in[7];
    const float* W_K      = (const float*)d_in[8];
    const float* W_in     = (const float*)d_in[9];
    const float* b_in     = (const float*)d_in[10];
    const float* W_f1     = (const float*)d_in[11];
    const float* b_f1     = (const float*)d_in[12];
    const float* W_f2     = (const float*)d_in[13];
    const float* b_f2     = (const float*)d_in[14];
    const float* W_out    = (const float*)d_in[15];
    const float* b_out    = (const float*)d_in[16];
    float* out = (float*)d_out;

    float* ws    = (float*)d_ws;
    float* xh    = ws;                                   // 10000*128
    float* Qbuf  = xh + N_ATOMS * F_DIM;                 // 10000*384
    float* Kbuf  = Qbuf + N_ATOMS * 384;                 // 10000*384
    float* alpha = Kbuf + N_ATOMS * 384;                 // 100000*12
    int*   seg   = (int*)(alpha + N_PAIR * 12);          // 10001 ints
    unsigned short* Bth = (unsigned short*)(seg + 10432); // 16384 bf16
    unsigned short* Btl = Bth + 16384;                    // 16384 bf16

    // h1 (100000*32 fp32 = 12.8 MB) staged in d_out (19.2M floats);
    // consumed by k_pair before k_agg overwrites d_out.
    float* h1g = out;

    k_seg<<<(N_ATOMS + 256) / 256, 256, 0, stream>>>(idx_i, seg);
    k_cvt_b<<<64, 256, 0, stream>>>(W_out, Bth, Btl);
    k_h1<<<(N_PAIR + 63) / 64, 256, 0, stream>>>(rbf_ij, W_f1, b_f1, h1g);
    k_gemm128<<<(N_ATOMS + 127) / 128, 256, 0, stream>>>(x, W_in, b_in, xh, N_ATOMS);
    k_qk<<<(N_ATOMS + 31) / 32, 384, 0, stream>>>(xh, W_Q, W_K, Qbuf, Kbuf);
    k_pair<<<(N_PAIR + 63) / 64, 384, 0, stream>>>(phi_r, pmask, idx_i, idx_j,
                                                   W_f2, b_f2, h1g, Qbuf, Kbuf, alpha);
    k_agg<<<N_ATOMS, 256, 0, stream>>>(xh, alpha, sph_ij, seg, idx_j, pmask,
                                       (unsigned int*)d_out);
    k_out_mfma<<<(R_OUT + 127) / 128, 256, 0, stream>>>((const unsigned int*)d_out,
                                                        Bth, Btl, b_out, out);
}